// Round 1
// baseline (2588.875 us; speedup 1.0000x reference)
//
#include <hip/hip_runtime.h>
#include <hip/hip_bf16.h>
#include <math.h>

// Problem constants: B=4, T=2048, C=1024, H=16, D=64
#define B_  4
#define T_  2048
#define C_  1024
#define NH  16
#define HD  64
#define M_  (B_ * T_)        // 8192 rows
#define N_QKV (3 * C_)       // 3072
#define SCALE 0.125f         // 1/sqrt(64)

typedef __attribute__((ext_vector_type(8))) short short8;
typedef __attribute__((ext_vector_type(4))) float f32x4;

__device__ __forceinline__ short f2bs(float f) {
  __hip_bfloat16 h = __float2bfloat16(f);
  return *reinterpret_cast<short*>(&h);
}
__device__ __forceinline__ float bs2f(short s) {
  unsigned u = ((unsigned)(unsigned short)s) << 16;
  return __builtin_bit_cast(float, u);
}

// ---------------------------------------------------------------------------
// GEMM: out[M,N] = A[M,1024] @ W[1024,N] + bias[N]
// A either f32 (cast to bf16 during staging) or bf16. W always f32 in global.
// 64x64 tile, BK=32, 256 threads = 4 waves (2x2), each wave 32x32 (2x2 frags
// of 16x16), mfma_f32_16x16x32_bf16.
// LDS: both A and B^T staged k-contiguous with row stride 40 (16B-aligned).
// ---------------------------------------------------------------------------
template<bool A_BF16, bool OUT_BF16>
__global__ __launch_bounds__(256) void gemm_bias_kernel(
    const void* __restrict__ Aptr, const float* __restrict__ Wptr,
    const float* __restrict__ bias, void* __restrict__ outptr, int N)
{
  constexpr int K = 1024;
  constexpr int LDT = 40;            // LDS row stride in bf16 elems
  __shared__ short As[64 * LDT];
  __shared__ short Bs[64 * LDT];

  const int tid  = threadIdx.x;
  const int lane = tid & 63;
  const int w    = tid >> 6;
  const int wr   = w >> 1, wc = w & 1;
  const int nblk = N / 64;
  const int m0 = (blockIdx.x / nblk) * 64;
  const int n0 = (blockIdx.x % nblk) * 64;

  f32x4 acc[2][2] = {};

  const int ar  = tid >> 2,  ac8 = (tid & 3) * 8;   // A stage: row 0..63, col8
  const int bk  = tid >> 3,  bn8 = (tid & 7) * 8;   // B stage: k 0..31, n8
  const int rl  = lane & 15, kg  = lane >> 4;

  for (int k0 = 0; k0 < K; k0 += 32) {
    __syncthreads();
    // ---- stage A tile [64 x 32] ----
    short8 av;
    if constexpr (A_BF16) {
      av = *reinterpret_cast<const short8*>(
              (const short*)Aptr + (size_t)(m0 + ar) * K + k0 + ac8);
    } else {
      const float* Af = (const float*)Aptr + (size_t)(m0 + ar) * K + k0 + ac8;
      f32x4 f0 = *reinterpret_cast<const f32x4*>(Af);
      f32x4 f1 = *reinterpret_cast<const f32x4*>(Af + 4);
      #pragma unroll
      for (int j = 0; j < 4; ++j) { av[j] = f2bs(f0[j]); av[4 + j] = f2bs(f1[j]); }
    }
    *reinterpret_cast<short8*>(&As[ar * LDT + ac8]) = av;
    // ---- stage B tile [32 x 64] transposed into Bs[col][k] ----
    {
      const float* Wf = Wptr + (size_t)(k0 + bk) * N + n0 + bn8;
      f32x4 w0 = *reinterpret_cast<const f32x4*>(Wf);
      f32x4 w1 = *reinterpret_cast<const f32x4*>(Wf + 4);
      #pragma unroll
      for (int j = 0; j < 4; ++j) {
        Bs[(bn8 + j) * LDT + bk]     = f2bs(w0[j]);
        Bs[(bn8 + 4 + j) * LDT + bk] = f2bs(w1[j]);
      }
    }
    __syncthreads();
    // ---- compute: 2x2 fragments, one K=32 mfma each ----
    short8 a0 = *reinterpret_cast<short8*>(&As[(wr * 32 +  0 + rl) * LDT + kg * 8]);
    short8 a1 = *reinterpret_cast<short8*>(&As[(wr * 32 + 16 + rl) * LDT + kg * 8]);
    short8 b0 = *reinterpret_cast<short8*>(&Bs[(wc * 32 +  0 + rl) * LDT + kg * 8]);
    short8 b1 = *reinterpret_cast<short8*>(&Bs[(wc * 32 + 16 + rl) * LDT + kg * 8]);
    acc[0][0] = __builtin_amdgcn_mfma_f32_16x16x32_bf16(a0, b0, acc[0][0], 0, 0, 0);
    acc[0][1] = __builtin_amdgcn_mfma_f32_16x16x32_bf16(a0, b1, acc[0][1], 0, 0, 0);
    acc[1][0] = __builtin_amdgcn_mfma_f32_16x16x32_bf16(a1, b0, acc[1][0], 0, 0, 0);
    acc[1][1] = __builtin_amdgcn_mfma_f32_16x16x32_bf16(a1, b1, acc[1][1], 0, 0, 0);
  }

  // ---- epilogue: C/D map col = lane&15, row = (lane>>4)*4 + r ----
  const int rg = lane >> 4;
  #pragma unroll
  for (int mi = 0; mi < 2; ++mi) {
    #pragma unroll
    for (int ni = 0; ni < 2; ++ni) {
      const int col = n0 + wc * 32 + ni * 16 + rl;
      const float bv = bias[col];
      #pragma unroll
      for (int r = 0; r < 4; ++r) {
        const int row = m0 + wr * 32 + mi * 16 + rg * 4 + r;
        const float v = acc[mi][ni][r] + bv;
        if constexpr (OUT_BF16)
          ((short*)outptr)[(size_t)row * N + col] = f2bs(v);
        else
          ((float*)outptr)[(size_t)row * N + col] = v;
      }
    }
  }
}

// ---------------------------------------------------------------------------
// Causal attention, vector f32 flash-style.
// Block = 256 thr = 4 waves; wave w handles q-row i0+w. K/V tiles of 64 keys
// staged to LDS (f32, stride 65 -> bank = (row+d)%32, conflict-free).
// QK: lane j owns key j (64 FMA over dims). PV: lane d owns dim d.
// Online softmax with wave shuffles. qkv layout: [B*T, 3072] bf16,
// q at +0, k at +1024, v at +2048, head h at h*64.
// ---------------------------------------------------------------------------
__global__ __launch_bounds__(256) void attn_kernel(
    const short* __restrict__ qkv, short* __restrict__ y)
{
  __shared__ float Ks[64 * 65];
  __shared__ float Vs[64 * 65];
  __shared__ float qs[4][64];
  __shared__ float ps[4][64];

  const int tid  = threadIdx.x;
  const int lane = tid & 63;
  const int w    = tid >> 6;
  const int bid  = blockIdx.x;
  const int bh   = bid >> 9;            // T/4 = 512 blocks per (b,h)
  const int i0   = (bid & 511) * 4;
  const int b    = bh >> 4, h = bh & 15;
  const int i    = i0 + w;              // this wave's query row

  // load q row (scale folded in)
  qs[w][lane] = bs2f(qkv[(size_t)(b * T_ + i) * N_QKV + h * HD + lane]) * SCALE;

  float m = -INFINITY, l = 0.f, o = 0.f;
  const int nkb = (i0 + 3) / 64 + 1;

  for (int kb = 0; kb < nkb; ++kb) {
    __syncthreads();
    // cooperative K/V tile load: thread -> key row tid>>2, 16 dims
    {
      const int kr = tid >> 2, d16 = (tid & 3) * 16;
      const size_t rb = (size_t)(b * T_ + kb * 64 + kr) * N_QKV + h * HD;
      const short8 k0v = *reinterpret_cast<const short8*>(qkv + rb + C_ + d16);
      const short8 k1v = *reinterpret_cast<const short8*>(qkv + rb + C_ + d16 + 8);
      const short8 v0v = *reinterpret_cast<const short8*>(qkv + rb + 2 * C_ + d16);
      const short8 v1v = *reinterpret_cast<const short8*>(qkv + rb + 2 * C_ + d16 + 8);
      #pragma unroll
      for (int j = 0; j < 8; ++j) {
        Ks[kr * 65 + d16 + j]     = bs2f(k0v[j]);
        Ks[kr * 65 + d16 + 8 + j] = bs2f(k1v[j]);
        Vs[kr * 65 + d16 + j]     = bs2f(v0v[j]);
        Vs[kr * 65 + d16 + 8 + j] = bs2f(v1v[j]);
      }
    }
    __syncthreads();

    // QK^T: lane owns key kj
    const int kj = kb * 64 + lane;
    float s = -INFINITY;
    if (kj <= i) {
      float a = 0.f;
      #pragma unroll
      for (int d = 0; d < 64; ++d) a += qs[w][d] * Ks[lane * 65 + d];
      s = a;
    }
    // wave max + online softmax update
    float tm = s;
    #pragma unroll
    for (int off = 32; off >= 1; off >>= 1) tm = fmaxf(tm, __shfl_xor(tm, off, 64));
    const float mn = fmaxf(m, tm);
    const float p = (kj <= i) ? __expf(s - mn) : 0.f;
    float psum = p;
    #pragma unroll
    for (int off = 32; off >= 1; off >>= 1) psum += __shfl_xor(psum, off, 64);
    const float c = (m == -INFINITY) ? 0.f : __expf(m - mn);
    l = l * c + psum;
    m = mn;
    ps[w][lane] = p;
    __syncthreads();
    // PV: lane owns dim = lane
    o *= c;
    #pragma unroll
    for (int j = 0; j < 64; ++j) o += ps[w][j] * Vs[j * 65 + lane];
  }

  y[(size_t)(b * T_ + i) * C_ + h * HD + lane] = f2bs(o / l);
}

extern "C" void kernel_launch(void* const* d_in, const int* in_sizes, int n_in,
                              void* d_out, int out_size, void* d_ws, size_t ws_size,
                              hipStream_t stream) {
  const float* x  = (const float*)d_in[0];
  const float* Wa = (const float*)d_in[1];
  const float* ba = (const float*)d_in[2];
  const float* Wp = (const float*)d_in[3];
  const float* bp = (const float*)d_in[4];

  short* qkvb = (short*)d_ws;                       // [8192, 3072] bf16
  short* yb   = qkvb + (size_t)M_ * N_QKV;          // [8192, 1024] bf16

  // 1) qkv = x @ W_attn + b_attn   (f32 in, bf16 out)
  gemm_bias_kernel<false, true><<<(M_ / 64) * (N_QKV / 64), 256, 0, stream>>>(
      x, Wa, ba, qkvb, N_QKV);
  // 2) y = causal_attention(q,k,v) (bf16 in, bf16 out)
  attn_kernel<<<B_ * NH * (T_ / 4), 256, 0, stream>>>(qkvb, yb);
  // 3) out = y @ W_proj + b_proj   (bf16 in, f32 out)
  gemm_bias_kernel<true, false><<<(M_ / 64) * (C_ / 64), 256, 0, stream>>>(
      yb, Wp, bp, d_out, C_);
}

// Round 2
// 570.909 us; speedup vs baseline: 4.5347x; 4.5347x over previous
//
#include <hip/hip_runtime.h>
#include <hip/hip_bf16.h>
#include <math.h>

// Problem constants: B=4, T=2048, C=1024, H=16, D=64
#define B_  4
#define T_  2048
#define C_  1024
#define NH  16
#define HD  64
#define M_  (B_ * T_)        // 8192 rows
#define N_QKV (3 * C_)       // 3072
#define SCALE 0.125f         // 1/sqrt(64)

typedef __attribute__((ext_vector_type(8))) short short8;
typedef __attribute__((ext_vector_type(4))) float f32x4;

__device__ __forceinline__ short f2bs(float f) {
  __hip_bfloat16 h = __float2bfloat16(f);
  return *reinterpret_cast<short*>(&h);
}

// ---------------------------------------------------------------------------
// GEMM: out[M,N] = A[M,1024] @ W[1024,N] + bias[N]   (unchanged from round 1)
// ---------------------------------------------------------------------------
template<bool A_BF16, bool OUT_BF16>
__global__ __launch_bounds__(256) void gemm_bias_kernel(
    const void* __restrict__ Aptr, const float* __restrict__ Wptr,
    const float* __restrict__ bias, void* __restrict__ outptr, int N)
{
  constexpr int K = 1024;
  constexpr int LDT = 40;            // LDS row stride in bf16 elems
  __shared__ short As[64 * LDT];
  __shared__ short Bs[64 * LDT];

  const int tid  = threadIdx.x;
  const int lane = tid & 63;
  const int w    = tid >> 6;
  const int wr   = w >> 1, wc = w & 1;
  const int nblk = N / 64;
  const int m0 = (blockIdx.x / nblk) * 64;
  const int n0 = (blockIdx.x % nblk) * 64;

  f32x4 acc[2][2] = {};

  const int ar  = tid >> 2,  ac8 = (tid & 3) * 8;   // A stage: row 0..63, col8
  const int bk  = tid >> 3,  bn8 = (tid & 7) * 8;   // B stage: k 0..31, n8
  const int rl  = lane & 15, kg  = lane >> 4;

  for (int k0 = 0; k0 < K; k0 += 32) {
    __syncthreads();
    // ---- stage A tile [64 x 32] ----
    short8 av;
    if constexpr (A_BF16) {
      av = *reinterpret_cast<const short8*>(
              (const short*)Aptr + (size_t)(m0 + ar) * K + k0 + ac8);
    } else {
      const float* Af = (const float*)Aptr + (size_t)(m0 + ar) * K + k0 + ac8;
      f32x4 f0 = *reinterpret_cast<const f32x4*>(Af);
      f32x4 f1 = *reinterpret_cast<const f32x4*>(Af + 4);
      #pragma unroll
      for (int j = 0; j < 4; ++j) { av[j] = f2bs(f0[j]); av[4 + j] = f2bs(f1[j]); }
    }
    *reinterpret_cast<short8*>(&As[ar * LDT + ac8]) = av;
    // ---- stage B tile [32 x 64] transposed into Bs[col][k] ----
    {
      const float* Wf = Wptr + (size_t)(k0 + bk) * N + n0 + bn8;
      f32x4 w0 = *reinterpret_cast<const f32x4*>(Wf);
      f32x4 w1 = *reinterpret_cast<const f32x4*>(Wf + 4);
      #pragma unroll
      for (int j = 0; j < 4; ++j) {
        Bs[(bn8 + j) * LDT + bk]     = f2bs(w0[j]);
        Bs[(bn8 + 4 + j) * LDT + bk] = f2bs(w1[j]);
      }
    }
    __syncthreads();
    // ---- compute: 2x2 fragments, one K=32 mfma each ----
    short8 a0 = *reinterpret_cast<short8*>(&As[(wr * 32 +  0 + rl) * LDT + kg * 8]);
    short8 a1 = *reinterpret_cast<short8*>(&As[(wr * 32 + 16 + rl) * LDT + kg * 8]);
    short8 b0 = *reinterpret_cast<short8*>(&Bs[(wc * 32 +  0 + rl) * LDT + kg * 8]);
    short8 b1 = *reinterpret_cast<short8*>(&Bs[(wc * 32 + 16 + rl) * LDT + kg * 8]);
    acc[0][0] = __builtin_amdgcn_mfma_f32_16x16x32_bf16(a0, b0, acc[0][0], 0, 0, 0);
    acc[0][1] = __builtin_amdgcn_mfma_f32_16x16x32_bf16(a0, b1, acc[0][1], 0, 0, 0);
    acc[1][0] = __builtin_amdgcn_mfma_f32_16x16x32_bf16(a1, b0, acc[1][0], 0, 0, 0);
    acc[1][1] = __builtin_amdgcn_mfma_f32_16x16x32_bf16(a1, b1, acc[1][1], 0, 0, 0);
  }

  // ---- epilogue: C/D map col = lane&15, row = (lane>>4)*4 + r ----
  const int rg = lane >> 4;
  #pragma unroll
  for (int mi = 0; mi < 2; ++mi) {
    #pragma unroll
    for (int ni = 0; ni < 2; ++ni) {
      const int col = n0 + wc * 32 + ni * 16 + rl;
      const float bv = bias[col];
      #pragma unroll
      for (int r = 0; r < 4; ++r) {
        const int row = m0 + wr * 32 + mi * 16 + rg * 4 + r;
        const float v = acc[mi][ni][r] + bv;
        if constexpr (OUT_BF16)
          ((short*)outptr)[(size_t)row * N + col] = f2bs(v);
        else
          ((float*)outptr)[(size_t)row * N + col] = v;
      }
    }
  }
}

// ---------------------------------------------------------------------------
// MFMA flash attention (causal). Block = 4 waves = 64 q-rows; KBLK = 64 keys.
// Per wave: 16 q-rows. Q in regs (2 A-frags). K tile row-major in LDS,
// V tile transposed in LDS (Vt[d][key]) so both B-frags are ds_read_b128.
// S/O kept in MFMA C/D layout: col = lane&15, row = (lane>>4)*4 + r.
// Online softmax with 16-lane-group shuffle reductions; P round-trips
// through per-wave LDS tile to convert to A-frag layout.
// ---------------------------------------------------------------------------
__global__ __launch_bounds__(256) void attn_mfma_kernel(
    const short* __restrict__ qkv, short* __restrict__ y)
{
  constexpr int LDK = 72, LDV = 72, LDP = 72;   // strides in shorts (144 B)
  __shared__ short Ks[64 * LDK];
  __shared__ short Vt[64 * LDV];
  __shared__ short Pl[4][16 * LDP];

  const int tid  = threadIdx.x;
  const int lane = tid & 63;
  const int w    = tid >> 6;
  const int rl   = lane & 15;
  const int kg   = lane >> 4;           // 0..3

  const int bid = blockIdx.x;
  const int it  = bid & 31;             // q-tile index (T/64 = 32)
  const int bh  = bid >> 5;
  const int b   = bh >> 4, h = bh & 15;
  const int i0  = it * 64;
  const int r0  = i0 + w * 16;          // this wave's first q-row

  // preload Q fragments (A-frag: row=rl, k = kg*8+j), 2 chunks of d
  const size_t qrow = (size_t)(b * T_ + r0 + rl) * N_QKV + h * HD;
  short8 qf0 = *reinterpret_cast<const short8*>(qkv + qrow + kg * 8);
  short8 qf1 = *reinterpret_cast<const short8*>(qkv + qrow + 32 + kg * 8);

  f32x4 o[4] = {};                      // O accum, dt = 0..3 (d col-tiles)
  float m[4], l[4];
  #pragma unroll
  for (int r = 0; r < 4; ++r) { m[r] = -INFINITY; l[r] = 0.f; }

  for (int kb = 0; kb <= it; ++kb) {
    __syncthreads();
    // ---- stage K tile [64 keys][64 d], row-major ----
    {
      const int key = tid >> 2, d16 = (tid & 3) * 16;
      const size_t rb = (size_t)(b * T_ + kb * 64 + key) * N_QKV + C_ + h * HD + d16;
      short8 k0 = *reinterpret_cast<const short8*>(qkv + rb);
      short8 k1 = *reinterpret_cast<const short8*>(qkv + rb + 8);
      *reinterpret_cast<short8*>(&Ks[key * LDK + d16])     = k0;
      *reinterpret_cast<short8*>(&Ks[key * LDK + d16 + 8]) = k1;
    }
    // ---- stage V transposed: Vt[d][key] ----
    {
      const int key = tid & 63, d16 = (tid >> 6) * 16;
      const size_t rb = (size_t)(b * T_ + kb * 64 + key) * N_QKV + 2 * C_ + h * HD + d16;
      short8 v0 = *reinterpret_cast<const short8*>(qkv + rb);
      short8 v1 = *reinterpret_cast<const short8*>(qkv + rb + 8);
      #pragma unroll
      for (int j = 0; j < 8; ++j) {
        Vt[(d16 + j) * LDV + key]     = v0[j];
        Vt[(d16 + 8 + j) * LDV + key] = v1[j];
      }
    }
    __syncthreads();

    // ---- QK^T: S[16 x 64] = 4 col-tiles x 2 k-chunks ----
    f32x4 s[4];
    #pragma unroll
    for (int c = 0; c < 4; ++c) {
      s[c] = (f32x4){0.f, 0.f, 0.f, 0.f};
      short8 k0 = *reinterpret_cast<short8*>(&Ks[(c * 16 + rl) * LDK + kg * 8]);
      short8 k1 = *reinterpret_cast<short8*>(&Ks[(c * 16 + rl) * LDK + 32 + kg * 8]);
      s[c] = __builtin_amdgcn_mfma_f32_16x16x32_bf16(qf0, k0, s[c], 0, 0, 0);
      s[c] = __builtin_amdgcn_mfma_f32_16x16x32_bf16(qf1, k1, s[c], 0, 0, 0);
    }

    // ---- scale (+ causal mask, only possible in last tile) ----
    if (kb == it) {
      #pragma unroll
      for (int c = 0; c < 4; ++c)
        #pragma unroll
        for (int r = 0; r < 4; ++r) {
          float sv = s[c][r] * SCALE;
          if (c * 16 + rl > w * 16 + kg * 4 + r) sv = -INFINITY;
          s[c][r] = sv;
        }
    } else {
      #pragma unroll
      for (int c = 0; c < 4; ++c)
        #pragma unroll
        for (int r = 0; r < 4; ++r) s[c][r] *= SCALE;
    }

    // ---- online softmax per q-row (rows live in 16-lane groups) ----
    #pragma unroll
    for (int r = 0; r < 4; ++r) {
      float mx = fmaxf(fmaxf(s[0][r], s[1][r]), fmaxf(s[2][r], s[3][r]));
      #pragma unroll
      for (int off = 8; off >= 1; off >>= 1) mx = fmaxf(mx, __shfl_xor(mx, off, 64));
      const float mn = fmaxf(m[r], mx);
      const float cr = __expf(m[r] - mn);   // m=-inf first iter -> 0
      float rs = 0.f;
      #pragma unroll
      for (int c = 0; c < 4; ++c) {
        const float p = __expf(s[c][r] - mn);
        s[c][r] = p;
        rs += p;
      }
      #pragma unroll
      for (int off = 8; off >= 1; off >>= 1) rs += __shfl_xor(rs, off, 64);
      l[r] = l[r] * cr + rs;
      m[r] = mn;
      o[0][r] *= cr; o[1][r] *= cr; o[2][r] *= cr; o[3][r] *= cr;
    }

    // ---- P -> LDS (convert D-layout to A-frag layout) ----
    #pragma unroll
    for (int c = 0; c < 4; ++c)
      #pragma unroll
      for (int r = 0; r < 4; ++r)
        Pl[w][(kg * 4 + r) * LDP + c * 16 + rl] = f2bs(s[c][r]);
    asm volatile("s_waitcnt lgkmcnt(0)" ::: "memory");

    // ---- PV: O[16 x 64] += P[16 x 64] * V[64 x 64] ----
    #pragma unroll
    for (int kk = 0; kk < 2; ++kk) {
      short8 pf = *reinterpret_cast<short8*>(&Pl[w][rl * LDP + kk * 32 + kg * 8]);
      #pragma unroll
      for (int dt = 0; dt < 4; ++dt) {
        short8 vf = *reinterpret_cast<short8*>(&Vt[(dt * 16 + rl) * LDV + kk * 32 + kg * 8]);
        o[dt] = __builtin_amdgcn_mfma_f32_16x16x32_bf16(pf, vf, o[dt], 0, 0, 0);
      }
    }
  }

  // ---- epilogue: y[row][h*64 + d] = o/l ----
  #pragma unroll
  for (int dt = 0; dt < 4; ++dt)
    #pragma unroll
    for (int r = 0; r < 4; ++r) {
      const int row = r0 + kg * 4 + r;
      y[(size_t)(b * T_ + row) * C_ + h * HD + dt * 16 + rl] = f2bs(o[dt][r] / l[r]);
    }
}

extern "C" void kernel_launch(void* const* d_in, const int* in_sizes, int n_in,
                              void* d_out, int out_size, void* d_ws, size_t ws_size,
                              hipStream_t stream) {
  const float* x  = (const float*)d_in[0];
  const float* Wa = (const float*)d_in[1];
  const float* ba = (const float*)d_in[2];
  const float* Wp = (const float*)d_in[3];
  const float* bp = (const float*)d_in[4];

  short* qkvb = (short*)d_ws;                       // [8192, 3072] bf16
  short* yb   = qkvb + (size_t)M_ * N_QKV;          // [8192, 1024] bf16

  // 1) qkv = x @ W_attn + b_attn   (f32 in, bf16 out)
  gemm_bias_kernel<false, true><<<(M_ / 64) * (N_QKV / 64), 256, 0, stream>>>(
      x, Wa, ba, qkvb, N_QKV);
  // 2) y = causal_attention(q,k,v) (bf16 in, bf16 out), MFMA flash
  attn_mfma_kernel<<<B_ * NH * (T_ / 64), 256, 0, stream>>>(qkvb, yb);
  // 3) out = y @ W_proj + b_proj   (bf16 in, f32 out)
  gemm_bias_kernel<true, false><<<(M_ / 64) * (C_ / 64), 256, 0, stream>>>(
      yb, Wp, bp, d_out, C_);
}

// Round 3
// 369.122 us; speedup vs baseline: 7.0136x; 1.5467x over previous
//
#include <hip/hip_runtime.h>
#include <hip/hip_bf16.h>
#include <math.h>

// Problem constants: B=4, T=2048, C=1024, H=16, D=64
#define B_  4
#define T_  2048
#define C_  1024
#define NH  16
#define HD  64
#define M_  (B_ * T_)        // 8192 rows
#define N_QKV (3 * C_)       // 3072
#define KDIM 1024
#define SCALE 0.125f         // 1/sqrt(64)

typedef __attribute__((ext_vector_type(8))) short short8;
typedef __attribute__((ext_vector_type(4))) short bs4;
typedef __attribute__((ext_vector_type(4))) float f32x4;

__device__ __forceinline__ short f2bs(float f) {
  __hip_bfloat16 h = __float2bfloat16(f);
  return *reinterpret_cast<short*>(&h);
}

__device__ __forceinline__ void gload16(const void* g, void* l) {
  __builtin_amdgcn_global_load_lds(
      (const __attribute__((address_space(1))) void*)g,
      (__attribute__((address_space(3))) void*)l, 16, 0, 0);
}

// ---------------------------------------------------------------------------
// Transpose + convert: W [KDIM][Ncols] f32  ->  Wt [Ncols][KDIM] bf16
// ---------------------------------------------------------------------------
__global__ __launch_bounds__(256) void wtrans_kernel(
    const float* __restrict__ W, short* __restrict__ Wt, int Ncols)
{
  __shared__ short t[32][33];
  const int nb = Ncols / 32;
  const int bn = blockIdx.x % nb, bk = blockIdx.x / nb;
  const int tid = threadIdx.x;
  const int r = tid >> 3, c4 = (tid & 7) * 4;
  f32x4 v = *reinterpret_cast<const f32x4*>(
      W + (size_t)(bk * 32 + r) * Ncols + bn * 32 + c4);
  #pragma unroll
  for (int j = 0; j < 4; ++j) t[r][c4 + j] = f2bs(v[j]);
  __syncthreads();
  bs4 o;
  #pragma unroll
  for (int j = 0; j < 4; ++j) o[j] = t[c4 + j][r];
  *reinterpret_cast<bs4*>(Wt + (size_t)(bn * 32 + r) * KDIM + bk * 32 + c4) = o;
}

// ---------------------------------------------------------------------------
// GEMM: out[M,N] = A[M,1024] @ Bt[N,1024]^T + bias[N]
// 128x128 tile, BK=32, 256 thr = 4 waves (2x2), 64x64 per wave (4x4 frags).
// B staged via global_load_lds (16B); A via global_load_lds if bf16, else
// reg-staged f32->bf16 with b128 LDS writes.
// LDS linear [128][32] shorts (64B rows); XOR swizzle on 16B slots:
//   slot s at row holds logical k-chunk s ^ ((row>>1)&3)  (2-way banks = free)
// Source addresses pre-swizzled (rule #21: both-sides-or-neither).
// ---------------------------------------------------------------------------
template<bool A_BF16, bool OUT_BF16>
__global__ __launch_bounds__(256) void gemm128_kernel(
    const void* __restrict__ Aptr, const short* __restrict__ Bt,
    const float* __restrict__ bias, void* __restrict__ outptr, int N)
{
  __shared__ short As[128 * 32];
  __shared__ short Bs[128 * 32];

  const int tid  = threadIdx.x;
  const int lane = tid & 63;
  const int w    = tid >> 6;
  const int wr   = w >> 1, wc = w & 1;
  const int rl   = lane & 15, kg = lane >> 4;
  const int nblk = N >> 7;
  const int m0 = (blockIdx.x / nblk) << 7;
  const int n0 = (blockIdx.x % nblk) << 7;

  f32x4 acc[4][4] = {};

  // ---- staging addresses ----
  // gload path: wave w, inst i in {0,1}: lane l covers LDS bytes
  // w*2048 + i*1024 + l*16  ->  row = w*32+i*16+(l>>2), slot = l&3.
  // slot s holds global chunk s ^ ((row>>1)&3); (row>>1)&3 == (l>>3)&3.
  const int srow = w * 32 + (lane >> 2);
  const int scol = ((lane & 3) ^ ((lane >> 3) & 3)) * 8;
  const short* pb0 = Bt + (size_t)(n0 + srow) * KDIM + scol;
  const short* pb1 = pb0 + (size_t)16 * KDIM;
  short* const lb0 = &Bs[w * 1024];
  short* const lb1 = &Bs[w * 1024 + 512];

  const short* pa0 = nullptr; const short* pa1 = nullptr;
  short* la0 = nullptr; short* la1 = nullptr;
  const float* paf = nullptr; short* lafA = nullptr; short* lafB = nullptr;
  if constexpr (A_BF16) {
    pa0 = (const short*)Aptr + (size_t)(m0 + srow) * KDIM + scol;
    pa1 = pa0 + (size_t)16 * KDIM;
    la0 = &As[w * 1024];
    la1 = &As[w * 1024 + 512];
  } else {
    // lane l: row = w*32 + (l>>1), half = l&1 (16 floats), phase = (row>>1)&3 = (l>>2)&3
    const int arow  = w * 32 + (lane >> 1);
    const int half  = lane & 1;
    const int phase = (lane >> 2) & 3;
    paf  = (const float*)Aptr + (size_t)(m0 + arow) * KDIM + half * 16;
    lafA = &As[arow * 32 + ((2 * half)     ^ phase) * 8];
    lafB = &As[arow * 32 + ((2 * half + 1) ^ phase) * 8];
  }

  // frag read: logical chunk kg at row base+rl lives in slot kg ^ ((rl>>1)&3)
  const int sread = (kg ^ ((rl >> 1) & 3)) * 8;

  for (int k0 = 0; k0 < KDIM; k0 += 32) {
    __syncthreads();
    if constexpr (A_BF16) {
      gload16(pa0 + k0, la0);
      gload16(pa1 + k0, la1);
    } else {
      const float* p = paf + k0;
      f32x4 f0 = *reinterpret_cast<const f32x4*>(p);
      f32x4 f1 = *reinterpret_cast<const f32x4*>(p + 4);
      f32x4 f2 = *reinterpret_cast<const f32x4*>(p + 8);
      f32x4 f3 = *reinterpret_cast<const f32x4*>(p + 12);
      short8 lo, hi;
      #pragma unroll
      for (int j = 0; j < 4; ++j) {
        lo[j] = f2bs(f0[j]); lo[4 + j] = f2bs(f1[j]);
        hi[j] = f2bs(f2[j]); hi[4 + j] = f2bs(f3[j]);
      }
      *reinterpret_cast<short8*>(lafA) = lo;
      *reinterpret_cast<short8*>(lafB) = hi;
    }
    gload16(pb0 + k0, lb0);
    gload16(pb1 + k0, lb1);
    __syncthreads();

    short8 af[4], bf[4];
    #pragma unroll
    for (int i = 0; i < 4; ++i) {
      af[i] = *reinterpret_cast<short8*>(&As[(wr * 64 + i * 16 + rl) * 32 + sread]);
      bf[i] = *reinterpret_cast<short8*>(&Bs[(wc * 64 + i * 16 + rl) * 32 + sread]);
    }
    #pragma unroll
    for (int mi = 0; mi < 4; ++mi)
      #pragma unroll
      for (int ni = 0; ni < 4; ++ni)
        acc[mi][ni] = __builtin_amdgcn_mfma_f32_16x16x32_bf16(
            af[mi], bf[ni], acc[mi][ni], 0, 0, 0);
  }

  // ---- epilogue: C/D map col = lane&15, row = (lane>>4)*4 + r ----
  #pragma unroll
  for (int ni = 0; ni < 4; ++ni) {
    const int col = n0 + wc * 64 + ni * 16 + rl;
    const float bv = bias[col];
    #pragma unroll
    for (int mi = 0; mi < 4; ++mi) {
      #pragma unroll
      for (int r = 0; r < 4; ++r) {
        const int row = m0 + wr * 64 + mi * 16 + kg * 4 + r;
        const float v = acc[mi][ni][r] + bv;
        if constexpr (OUT_BF16)
          ((short*)outptr)[(size_t)row * N + col] = f2bs(v);
        else
          ((float*)outptr)[(size_t)row * N + col] = v;
      }
    }
  }
}

// ---------------------------------------------------------------------------
// MFMA flash attention (causal) — unchanged from round 2.
// ---------------------------------------------------------------------------
__global__ __launch_bounds__(256) void attn_mfma_kernel(
    const short* __restrict__ qkv, short* __restrict__ y)
{
  constexpr int LDK = 72, LDV = 72, LDP = 72;
  __shared__ short Ks[64 * LDK];
  __shared__ short Vt[64 * LDV];
  __shared__ short Pl[4][16 * LDP];

  const int tid  = threadIdx.x;
  const int lane = tid & 63;
  const int w    = tid >> 6;
  const int rl   = lane & 15;
  const int kg   = lane >> 4;

  const int bid = blockIdx.x;
  const int it  = bid & 31;
  const int bh  = bid >> 5;
  const int b   = bh >> 4, h = bh & 15;
  const int i0  = it * 64;
  const int r0  = i0 + w * 16;

  const size_t qrow = (size_t)(b * T_ + r0 + rl) * N_QKV + h * HD;
  short8 qf0 = *reinterpret_cast<const short8*>(qkv + qrow + kg * 8);
  short8 qf1 = *reinterpret_cast<const short8*>(qkv + qrow + 32 + kg * 8);

  f32x4 o[4] = {};
  float m[4], l[4];
  #pragma unroll
  for (int r = 0; r < 4; ++r) { m[r] = -INFINITY; l[r] = 0.f; }

  for (int kb = 0; kb <= it; ++kb) {
    __syncthreads();
    {
      const int key = tid >> 2, d16 = (tid & 3) * 16;
      const size_t rb = (size_t)(b * T_ + kb * 64 + key) * N_QKV + C_ + h * HD + d16;
      short8 k0 = *reinterpret_cast<const short8*>(qkv + rb);
      short8 k1 = *reinterpret_cast<const short8*>(qkv + rb + 8);
      *reinterpret_cast<short8*>(&Ks[key * LDK + d16])     = k0;
      *reinterpret_cast<short8*>(&Ks[key * LDK + d16 + 8]) = k1;
    }
    {
      const int key = tid & 63, d16 = (tid >> 6) * 16;
      const size_t rb = (size_t)(b * T_ + kb * 64 + key) * N_QKV + 2 * C_ + h * HD + d16;
      short8 v0 = *reinterpret_cast<const short8*>(qkv + rb);
      short8 v1 = *reinterpret_cast<const short8*>(qkv + rb + 8);
      #pragma unroll
      for (int j = 0; j < 8; ++j) {
        Vt[(d16 + j) * LDV + key]     = v0[j];
        Vt[(d16 + 8 + j) * LDV + key] = v1[j];
      }
    }
    __syncthreads();

    f32x4 s[4];
    #pragma unroll
    for (int c = 0; c < 4; ++c) {
      s[c] = (f32x4){0.f, 0.f, 0.f, 0.f};
      short8 k0 = *reinterpret_cast<short8*>(&Ks[(c * 16 + rl) * LDK + kg * 8]);
      short8 k1 = *reinterpret_cast<short8*>(&Ks[(c * 16 + rl) * LDK + 32 + kg * 8]);
      s[c] = __builtin_amdgcn_mfma_f32_16x16x32_bf16(qf0, k0, s[c], 0, 0, 0);
      s[c] = __builtin_amdgcn_mfma_f32_16x16x32_bf16(qf1, k1, s[c], 0, 0, 0);
    }

    if (kb == it) {
      #pragma unroll
      for (int c = 0; c < 4; ++c)
        #pragma unroll
        for (int r = 0; r < 4; ++r) {
          float sv = s[c][r] * SCALE;
          if (c * 16 + rl > w * 16 + kg * 4 + r) sv = -INFINITY;
          s[c][r] = sv;
        }
    } else {
      #pragma unroll
      for (int c = 0; c < 4; ++c)
        #pragma unroll
        for (int r = 0; r < 4; ++r) s[c][r] *= SCALE;
    }

    #pragma unroll
    for (int r = 0; r < 4; ++r) {
      float mx = fmaxf(fmaxf(s[0][r], s[1][r]), fmaxf(s[2][r], s[3][r]));
      #pragma unroll
      for (int off = 8; off >= 1; off >>= 1) mx = fmaxf(mx, __shfl_xor(mx, off, 64));
      const float mn = fmaxf(m[r], mx);
      const float cr = __expf(m[r] - mn);
      float rs = 0.f;
      #pragma unroll
      for (int c = 0; c < 4; ++c) {
        const float p = __expf(s[c][r] - mn);
        s[c][r] = p;
        rs += p;
      }
      #pragma unroll
      for (int off = 8; off >= 1; off >>= 1) rs += __shfl_xor(rs, off, 64);
      l[r] = l[r] * cr + rs;
      m[r] = mn;
      o[0][r] *= cr; o[1][r] *= cr; o[2][r] *= cr; o[3][r] *= cr;
    }

    #pragma unroll
    for (int c = 0; c < 4; ++c)
      #pragma unroll
      for (int r = 0; r < 4; ++r)
        Pl[w][(kg * 4 + r) * LDP + c * 16 + rl] = f2bs(s[c][r]);
    asm volatile("s_waitcnt lgkmcnt(0)" ::: "memory");

    #pragma unroll
    for (int kk = 0; kk < 2; ++kk) {
      short8 pf = *reinterpret_cast<short8*>(&Pl[w][rl * LDP + kk * 32 + kg * 8]);
      #pragma unroll
      for (int dt = 0; dt < 4; ++dt) {
        short8 vf = *reinterpret_cast<short8*>(&Vt[(dt * 16 + rl) * LDV + kk * 32 + kg * 8]);
        o[dt] = __builtin_amdgcn_mfma_f32_16x16x32_bf16(pf, vf, o[dt], 0, 0, 0);
      }
    }
  }

  #pragma unroll
  for (int dt = 0; dt < 4; ++dt)
    #pragma unroll
    for (int r = 0; r < 4; ++r) {
      const int row = r0 + kg * 4 + r;
      y[(size_t)(b * T_ + row) * C_ + h * HD + dt * 16 + rl] = f2bs(o[dt][r] / l[r]);
    }
}

extern "C" void kernel_launch(void* const* d_in, const int* in_sizes, int n_in,
                              void* d_out, int out_size, void* d_ws, size_t ws_size,
                              hipStream_t stream) {
  const float* x  = (const float*)d_in[0];
  const float* Wa = (const float*)d_in[1];
  const float* ba = (const float*)d_in[2];
  const float* Wp = (const float*)d_in[3];
  const float* bp = (const float*)d_in[4];

  short* qkvb = (short*)d_ws;                       // [8192,3072] bf16 (50.3MB)
  short* yb   = qkvb + (size_t)M_ * N_QKV;          // [8192,1024] bf16 (16.8MB)
  short* WaT  = yb + (size_t)M_ * C_;               // [3072,1024] bf16 (6.3MB)
  short* WpT  = WaT;                                // overlaid: written after gemm1

  // W_attn^T -> bf16
  wtrans_kernel<<<(KDIM / 32) * (N_QKV / 32), 256, 0, stream>>>(Wa, WaT, N_QKV);
  // 1) qkv = x @ W_attn + b_attn   (f32 A reg-staged, bf16 out)
  gemm128_kernel<false, true><<<(M_ / 128) * (N_QKV / 128), 256, 0, stream>>>(
      x, WaT, ba, qkvb, N_QKV);
  // W_proj^T -> bf16 (into WaT region, now dead)
  wtrans_kernel<<<(KDIM / 32) * (C_ / 32), 256, 0, stream>>>(Wp, WpT, C_);
  // 2) y = causal_attention(q,k,v)
  attn_mfma_kernel<<<B_ * NH * (T_ / 64), 256, 0, stream>>>(qkvb, yb);
  // 3) out = y @ W_proj + b_proj   (bf16 A via gload_lds, f32 out)
  gemm128_kernel<true, false><<<(M_ / 128) * (C_ / 128), 256, 0, stream>>>(
      yb, WpT, bp, d_out, C_);
}

// Round 4
// 243.676 us; speedup vs baseline: 10.6242x; 1.5148x over previous
//
#include <hip/hip_runtime.h>
#include <hip/hip_bf16.h>
#include <math.h>

// Problem constants: B=4, T=2048, C=1024, H=16, D=64
#define B_  4
#define T_  2048
#define C_  1024
#define NH  16
#define HD  64
#define M_  (B_ * T_)        // 8192 rows
#define N_QKV (3 * C_)       // 3072
#define KDIM 1024
#define SCALE 0.125f         // 1/sqrt(64)

typedef __attribute__((ext_vector_type(8))) short short8;
typedef __attribute__((ext_vector_type(4))) short bs4;
typedef __attribute__((ext_vector_type(4))) float f32x4;

__device__ __forceinline__ short f2bs(float f) {
  __hip_bfloat16 h = __float2bfloat16(f);
  return *reinterpret_cast<short*>(&h);
}

__device__ __forceinline__ void gload16(const void* g, void* l) {
  __builtin_amdgcn_global_load_lds(
      (const __attribute__((address_space(1))) void*)g,
      (__attribute__((address_space(3))) void*)l, 16, 0, 0);
}

// ---------------------------------------------------------------------------
// Transpose + convert: W [KDIM][Ncols] f32  ->  Wt [Ncols][KDIM] bf16
// ---------------------------------------------------------------------------
__global__ __launch_bounds__(256) void wtrans_kernel(
    const float* __restrict__ W, short* __restrict__ Wt, int Ncols)
{
  __shared__ short t[32][33];
  const int nb = Ncols / 32;
  const int bn = blockIdx.x % nb, bk = blockIdx.x / nb;
  const int tid = threadIdx.x;
  const int r = tid >> 3, c4 = (tid & 7) * 4;
  f32x4 v = *reinterpret_cast<const f32x4*>(
      W + (size_t)(bk * 32 + r) * Ncols + bn * 32 + c4);
  #pragma unroll
  for (int j = 0; j < 4; ++j) t[r][c4 + j] = f2bs(v[j]);
  __syncthreads();
  bs4 o;
  #pragma unroll
  for (int j = 0; j < 4; ++j) o[j] = t[c4 + j][r];
  *reinterpret_cast<bs4*>(Wt + (size_t)(bn * 32 + r) * KDIM + bk * 32 + c4) = o;
}

// ---------------------------------------------------------------------------
// GEMM: out[M,N] = A[M,1024] @ Bt[N,1024]^T + bias[N]   (unchanged round 3)
// ---------------------------------------------------------------------------
template<bool A_BF16, bool OUT_BF16>
__global__ __launch_bounds__(256) void gemm128_kernel(
    const void* __restrict__ Aptr, const short* __restrict__ Bt,
    const float* __restrict__ bias, void* __restrict__ outptr, int N)
{
  __shared__ short As[128 * 32];
  __shared__ short Bs[128 * 32];

  const int tid  = threadIdx.x;
  const int lane = tid & 63;
  const int w    = tid >> 6;
  const int wr   = w >> 1, wc = w & 1;
  const int rl   = lane & 15, kg = lane >> 4;
  const int nblk = N >> 7;
  const int m0 = (blockIdx.x / nblk) << 7;
  const int n0 = (blockIdx.x % nblk) << 7;

  f32x4 acc[4][4] = {};

  const int srow = w * 32 + (lane >> 2);
  const int scol = ((lane & 3) ^ ((lane >> 3) & 3)) * 8;
  const short* pb0 = Bt + (size_t)(n0 + srow) * KDIM + scol;
  const short* pb1 = pb0 + (size_t)16 * KDIM;
  short* const lb0 = &Bs[w * 1024];
  short* const lb1 = &Bs[w * 1024 + 512];

  const short* pa0 = nullptr; const short* pa1 = nullptr;
  short* la0 = nullptr; short* la1 = nullptr;
  const float* paf = nullptr; short* lafA = nullptr; short* lafB = nullptr;
  if constexpr (A_BF16) {
    pa0 = (const short*)Aptr + (size_t)(m0 + srow) * KDIM + scol;
    pa1 = pa0 + (size_t)16 * KDIM;
    la0 = &As[w * 1024];
    la1 = &As[w * 1024 + 512];
  } else {
    const int arow  = w * 32 + (lane >> 1);
    const int half  = lane & 1;
    const int phase = (lane >> 2) & 3;
    paf  = (const float*)Aptr + (size_t)(m0 + arow) * KDIM + half * 16;
    lafA = &As[arow * 32 + ((2 * half)     ^ phase) * 8];
    lafB = &As[arow * 32 + ((2 * half + 1) ^ phase) * 8];
  }

  const int sread = (kg ^ ((rl >> 1) & 3)) * 8;

  for (int k0 = 0; k0 < KDIM; k0 += 32) {
    __syncthreads();
    if constexpr (A_BF16) {
      gload16(pa0 + k0, la0);
      gload16(pa1 + k0, la1);
    } else {
      const float* p = paf + k0;
      f32x4 f0 = *reinterpret_cast<const f32x4*>(p);
      f32x4 f1 = *reinterpret_cast<const f32x4*>(p + 4);
      f32x4 f2 = *reinterpret_cast<const f32x4*>(p + 8);
      f32x4 f3 = *reinterpret_cast<const f32x4*>(p + 12);
      short8 lo, hi;
      #pragma unroll
      for (int j = 0; j < 4; ++j) {
        lo[j] = f2bs(f0[j]); lo[4 + j] = f2bs(f1[j]);
        hi[j] = f2bs(f2[j]); hi[4 + j] = f2bs(f3[j]);
      }
      *reinterpret_cast<short8*>(lafA) = lo;
      *reinterpret_cast<short8*>(lafB) = hi;
    }
    gload16(pb0 + k0, lb0);
    gload16(pb1 + k0, lb1);
    __syncthreads();

    short8 af[4], bf[4];
    #pragma unroll
    for (int i = 0; i < 4; ++i) {
      af[i] = *reinterpret_cast<short8*>(&As[(wr * 64 + i * 16 + rl) * 32 + sread]);
      bf[i] = *reinterpret_cast<short8*>(&Bs[(wc * 64 + i * 16 + rl) * 32 + sread]);
    }
    #pragma unroll
    for (int mi = 0; mi < 4; ++mi)
      #pragma unroll
      for (int ni = 0; ni < 4; ++ni)
        acc[mi][ni] = __builtin_amdgcn_mfma_f32_16x16x32_bf16(
            af[mi], bf[ni], acc[mi][ni], 0, 0, 0);
  }

  #pragma unroll
  for (int ni = 0; ni < 4; ++ni) {
    const int col = n0 + wc * 64 + ni * 16 + rl;
    const float bv = bias[col];
    #pragma unroll
    for (int mi = 0; mi < 4; ++mi) {
      #pragma unroll
      for (int r = 0; r < 4; ++r) {
        const int row = m0 + wr * 64 + mi * 16 + kg * 4 + r;
        const float v = acc[mi][ni][r] + bv;
        if constexpr (OUT_BF16)
          ((short*)outptr)[(size_t)row * N + col] = f2bs(v);
        else
          ((float*)outptr)[(size_t)row * N + col] = v;
      }
    }
  }
}

// ---------------------------------------------------------------------------
// MFMA flash attention v2 (causal). Block = 4 waves, wave owns 32 q-rows;
// block processes q-tiles {pair, 15-pair} (exactly 34 k-tiles/block).
// K double-buffered via global_load_lds (XOR-swizzled source, linear dest);
// V double-buffered reg-staged transposed (issue at tile top, write at tile
// bottom); rowsum via MFMA-with-ones; 1 barrier per k-tile.
// bid = pair*64 + bh  ->  all 8 blocks of a (b,h) share an XCD.
// ---------------------------------------------------------------------------
__global__ __launch_bounds__(256) void attn_mfma2_kernel(
    const short* __restrict__ qkv, short* __restrict__ y)
{
  __shared__ short Ks[2][64 * 64];
  __shared__ short Vt[2][64 * 64];
  __shared__ short Pl[4][32 * 72];

  const int tid  = threadIdx.x;
  const int lane = tid & 63;
  const int w    = tid >> 6;
  const int rl   = lane & 15;
  const int kg   = lane >> 4;

  const int bid  = blockIdx.x;
  const int pair = bid >> 6;            // 0..7
  const int bh   = bid & 63;
  const int b    = bh >> 4, h = bh & 15;
  const size_t bT = (size_t)b * T_;

  short8 ones;
  #pragma unroll
  for (int j = 0; j < 8; ++j) ones[j] = (short)0x3F80;

  // K staging: linear pos p: row=p>>3, phys slot=p&7, logical=phys^(row&7)
  const int kr0 = tid >> 3;
  const int kl0 = (tid & 7) ^ ((tid >> 3) & 7);
  const int kr1 = (tid + 256) >> 3;
  const int kl1 = (tid & 7) ^ (((tid + 256) >> 3) & 7);
  const size_t kbase0 = (bT + kr0) * N_QKV + C_ + h * HD + kl0 * 8;
  const size_t kbase1 = (bT + kr1) * N_QKV + C_ + h * HD + kl1 * 8;
  short* const kdst0 = &Ks[0][(w * 64) * 8];
  short* const kdst1 = &Ks[0][(w * 64 + 256) * 8];

  // V staging: thread covers key=tid&63, d in [w*16, w*16+16)
  const int vkey = tid & 63;
  const int vd16 = (tid >> 6) * 16;
  const size_t vbase = (bT + vkey) * N_QKV + 2 * C_ + h * HD + vd16;

  const int fslot0 = ((0 + kg) ^ (rl & 7)) * 8;   // k-chunk 0 phys slot
  const int fslot1 = ((4 + kg) ^ (rl & 7)) * 8;   // k-chunk 1 phys slot

  #pragma unroll 1
  for (int sel = 0; sel < 2; ++sel) {
    const int qi  = sel ? (15 - pair) : pair;
    const int nkb = 2 * qi + 2;
    const int wq0 = qi * 128 + w * 32;

    short8 qf[2][2];
    #pragma unroll
    for (int rt = 0; rt < 2; ++rt) {
      const size_t qrow = (bT + wq0 + rt * 16 + rl) * N_QKV + h * HD;
      qf[rt][0] = *reinterpret_cast<const short8*>(qkv + qrow + kg * 8);
      qf[rt][1] = *reinterpret_cast<const short8*>(qkv + qrow + 32 + kg * 8);
    }

    f32x4 o[2][4] = {};
    float m[2][4], l[2][4];
    #pragma unroll
    for (int rt = 0; rt < 2; ++rt)
      #pragma unroll
      for (int r = 0; r < 4; ++r) { m[rt][r] = -INFINITY; l[rt][r] = 0.f; }

    // prologue: stage tile 0 into buffer 0
    {
      gload16(qkv + kbase0, kdst0);
      gload16(qkv + kbase1, kdst1);
      short8 va = *reinterpret_cast<const short8*>(qkv + vbase);
      short8 vb = *reinterpret_cast<const short8*>(qkv + vbase + 8);
      #pragma unroll
      for (int j = 0; j < 8; ++j) {
        Vt[0][(vd16 + j) * 64 + (((vkey >> 3) ^ j) << 3) + (vkey & 7)]     = va[j];
        Vt[0][(vd16 + 8 + j) * 64 + (((vkey >> 3) ^ j) << 3) + (vkey & 7)] = vb[j];
      }
    }
    __syncthreads();

    int cur = 0;
    for (int kb = 0; kb < nkb; ++kb) {
      const bool more = (kb + 1 < nkb);
      short8 va, vb;
      if (more) {
        const size_t koff = (size_t)(kb + 1) * 64 * N_QKV;
        gload16(qkv + kbase0 + koff, kdst0 + (cur ^ 1) * 4096);
        gload16(qkv + kbase1 + koff, kdst1 + (cur ^ 1) * 4096);
        va = *reinterpret_cast<const short8*>(qkv + vbase + koff);
        vb = *reinterpret_cast<const short8*>(qkv + vbase + koff + 8);
      }

      const int kmin = kb * 64;
      if (kmin <= wq0 + 31) {
        const short* ksc = &Ks[cur][0];
        const short* vtc = &Vt[cur][0];

        // QK^T
        f32x4 s[2][4];
        #pragma unroll
        for (int c = 0; c < 4; ++c) {
          short8 kf0 = *reinterpret_cast<const short8*>(&ksc[(c * 16 + rl) * 64 + fslot0]);
          short8 kf1 = *reinterpret_cast<const short8*>(&ksc[(c * 16 + rl) * 64 + fslot1]);
          #pragma unroll
          for (int rt = 0; rt < 2; ++rt) {
            f32x4 acc = {0.f, 0.f, 0.f, 0.f};
            acc = __builtin_amdgcn_mfma_f32_16x16x32_bf16(qf[rt][0], kf0, acc, 0, 0, 0);
            acc = __builtin_amdgcn_mfma_f32_16x16x32_bf16(qf[rt][1], kf1, acc, 0, 0, 0);
            s[rt][c] = acc;
          }
        }

        // scale + causal mask
        const bool needmask = (kmin + 63 > wq0);
        #pragma unroll
        for (int rt = 0; rt < 2; ++rt)
          #pragma unroll
          for (int c = 0; c < 4; ++c)
            #pragma unroll
            for (int r = 0; r < 4; ++r) {
              float sv = s[rt][c][r] * SCALE;
              if (needmask &&
                  (kmin + c * 16 + rl > wq0 + rt * 16 + kg * 4 + r))
                sv = -INFINITY;
              s[rt][c][r] = sv;
            }

        // softmax: max reduce, rescale o, exp, write P
        float cr[2][4];
        #pragma unroll
        for (int rt = 0; rt < 2; ++rt)
          #pragma unroll
          for (int r = 0; r < 4; ++r) {
            float mx = fmaxf(fmaxf(s[rt][0][r], s[rt][1][r]),
                             fmaxf(s[rt][2][r], s[rt][3][r]));
            #pragma unroll
            for (int off = 8; off >= 1; off >>= 1)
              mx = fmaxf(mx, __shfl_xor(mx, off, 64));
            const float mn = fmaxf(m[rt][r], mx);
            cr[rt][r] = __expf(m[rt][r] - mn);
            m[rt][r] = mn;
            #pragma unroll
            for (int c = 0; c < 4; ++c)
              s[rt][c][r] = __expf(s[rt][c][r] - mn);
          }
        #pragma unroll
        for (int rt = 0; rt < 2; ++rt)
          #pragma unroll
          for (int dt = 0; dt < 4; ++dt)
            #pragma unroll
            for (int r = 0; r < 4; ++r)
              o[rt][dt][r] *= cr[rt][r];          // rescale BEFORE PV
        #pragma unroll
        for (int rt = 0; rt < 2; ++rt)
          #pragma unroll
          for (int c = 0; c < 4; ++c)
            #pragma unroll
            for (int r = 0; r < 4; ++r)
              Pl[w][(rt * 16 + kg * 4 + r) * 72 + c * 16 + rl] = f2bs(s[rt][c][r]);
        asm volatile("s_waitcnt lgkmcnt(0)" ::: "memory");

        // PV + rowsum-by-ones
        f32x4 lsum[2] = {};
        #pragma unroll
        for (int kk = 0; kk < 2; ++kk) {
          short8 pf[2];
          #pragma unroll
          for (int rt = 0; rt < 2; ++rt)
            pf[rt] = *reinterpret_cast<const short8*>(
                &Pl[w][(rt * 16 + rl) * 72 + kk * 32 + kg * 8]);
          const int fs = kk ? fslot1 : fslot0;
          #pragma unroll
          for (int dt = 0; dt < 4; ++dt) {
            short8 vf = *reinterpret_cast<const short8*>(&vtc[(dt * 16 + rl) * 64 + fs]);
            #pragma unroll
            for (int rt = 0; rt < 2; ++rt)
              o[rt][dt] = __builtin_amdgcn_mfma_f32_16x16x32_bf16(pf[rt], vf, o[rt][dt], 0, 0, 0);
          }
          #pragma unroll
          for (int rt = 0; rt < 2; ++rt)
            lsum[rt] = __builtin_amdgcn_mfma_f32_16x16x32_bf16(pf[rt], ones, lsum[rt], 0, 0, 0);
        }
        #pragma unroll
        for (int rt = 0; rt < 2; ++rt)
          #pragma unroll
          for (int r = 0; r < 4; ++r)
            l[rt][r] = l[rt][r] * cr[rt][r] + lsum[rt][r];
      }

      if (more) {
        #pragma unroll
        for (int j = 0; j < 8; ++j) {
          Vt[cur ^ 1][(vd16 + j) * 64 + (((vkey >> 3) ^ j) << 3) + (vkey & 7)]     = va[j];
          Vt[cur ^ 1][(vd16 + 8 + j) * 64 + (((vkey >> 3) ^ j) << 3) + (vkey & 7)] = vb[j];
        }
      }
      __syncthreads();
      cur ^= 1;
    }

    // epilogue
    #pragma unroll
    for (int rt = 0; rt < 2; ++rt)
      #pragma unroll
      for (int dt = 0; dt < 4; ++dt)
        #pragma unroll
        for (int r = 0; r < 4; ++r) {
          const int row = wq0 + rt * 16 + kg * 4 + r;
          y[(bT + row) * C_ + h * HD + dt * 16 + rl] = f2bs(o[rt][dt][r] / l[rt][r]);
        }
  }
}

extern "C" void kernel_launch(void* const* d_in, const int* in_sizes, int n_in,
                              void* d_out, int out_size, void* d_ws, size_t ws_size,
                              hipStream_t stream) {
  const float* x  = (const float*)d_in[0];
  const float* Wa = (const float*)d_in[1];
  const float* ba = (const float*)d_in[2];
  const float* Wp = (const float*)d_in[3];
  const float* bp = (const float*)d_in[4];

  short* qkvb = (short*)d_ws;                       // [8192,3072] bf16 (50.3MB)
  short* yb   = qkvb + (size_t)M_ * N_QKV;          // [8192,1024] bf16 (16.8MB)
  short* WaT  = yb + (size_t)M_ * C_;               // [3072,1024] bf16 (6.3MB)
  short* WpT  = WaT;                                // overlaid

  wtrans_kernel<<<(KDIM / 32) * (N_QKV / 32), 256, 0, stream>>>(Wa, WaT, N_QKV);
  gemm128_kernel<false, true><<<(M_ / 128) * (N_QKV / 128), 256, 0, stream>>>(
      x, WaT, ba, qkvb, N_QKV);
  wtrans_kernel<<<(KDIM / 32) * (C_ / 32), 256, 0, stream>>>(Wp, WpT, C_);
  attn_mfma2_kernel<<<8 * B_ * NH, 256, 0, stream>>>(qkvb, yb);
  gemm128_kernel<true, false><<<(M_ / 128) * (C_ / 128), 256, 0, stream>>>(
      yb, WpT, bp, d_out, C_);
}

// Round 5
// 235.351 us; speedup vs baseline: 11.0001x; 1.0354x over previous
//
#include <hip/hip_runtime.h>
#include <hip/hip_bf16.h>
#include <math.h>

// Problem constants: B=4, T=2048, C=1024, H=16, D=64
#define B_  4
#define T_  2048
#define C_  1024
#define NH  16
#define HD  64
#define M_  (B_ * T_)        // 8192 rows
#define N_QKV (3 * C_)       // 3072
#define KDIM 1024
#define SCALE2 0.18033688011112042f   // (1/sqrt(64)) * log2(e)

typedef __attribute__((ext_vector_type(8))) short short8;
typedef __attribute__((ext_vector_type(4))) short bs4;
typedef __attribute__((ext_vector_type(4))) float f32x4;
typedef __attribute__((ext_vector_type(16))) float f32x16;
typedef __attribute__((ext_vector_type(4))) unsigned u32x4;

__device__ __forceinline__ short f2bs(float f) {
  __hip_bfloat16 h = __float2bfloat16(f);
  return *reinterpret_cast<short*>(&h);
}
__device__ __forceinline__ unsigned pack2(float a, float b) {
  return (unsigned)(unsigned short)f2bs(a) | ((unsigned)(unsigned short)f2bs(b) << 16);
}

__device__ __forceinline__ void gload16(const void* g, void* l) {
  __builtin_amdgcn_global_load_lds(
      (const __attribute__((address_space(1))) void*)g,
      (__attribute__((address_space(3))) void*)l, 16, 0, 0);
}

// ---------------------------------------------------------------------------
// Transpose + convert: W [KDIM][Ncols] f32  ->  Wt [Ncols][KDIM] bf16
// ---------------------------------------------------------------------------
__global__ __launch_bounds__(256) void wtrans_kernel(
    const float* __restrict__ W, short* __restrict__ Wt, int Ncols)
{
  __shared__ short t[32][33];
  const int nb = Ncols / 32;
  const int bn = blockIdx.x % nb, bk = blockIdx.x / nb;
  const int tid = threadIdx.x;
  const int r = tid >> 3, c4 = (tid & 7) * 4;
  f32x4 v = *reinterpret_cast<const f32x4*>(
      W + (size_t)(bk * 32 + r) * Ncols + bn * 32 + c4);
  #pragma unroll
  for (int j = 0; j < 4; ++j) t[r][c4 + j] = f2bs(v[j]);
  __syncthreads();
  bs4 o;
  #pragma unroll
  for (int j = 0; j < 4; ++j) o[j] = t[c4 + j][r];
  *reinterpret_cast<bs4*>(Wt + (size_t)(bn * 32 + r) * KDIM + bk * 32 + c4) = o;
}

// ---------------------------------------------------------------------------
// GEMM: out[M,N] = A[M,1024] @ Bt[N,1024]^T + bias[N]   (unchanged)
// ---------------------------------------------------------------------------
template<bool A_BF16, bool OUT_BF16>
__global__ __launch_bounds__(256) void gemm128_kernel(
    const void* __restrict__ Aptr, const short* __restrict__ Bt,
    const float* __restrict__ bias, void* __restrict__ outptr, int N)
{
  __shared__ short As[128 * 32];
  __shared__ short Bs[128 * 32];

  const int tid  = threadIdx.x;
  const int lane = tid & 63;
  const int w    = tid >> 6;
  const int wr   = w >> 1, wc = w & 1;
  const int rl   = lane & 15, kg = lane >> 4;
  const int nblk = N >> 7;
  const int m0 = (blockIdx.x / nblk) << 7;
  const int n0 = (blockIdx.x % nblk) << 7;

  f32x4 acc[4][4] = {};

  const int srow = w * 32 + (lane >> 2);
  const int scol = ((lane & 3) ^ ((lane >> 3) & 3)) * 8;
  const short* pb0 = Bt + (size_t)(n0 + srow) * KDIM + scol;
  const short* pb1 = pb0 + (size_t)16 * KDIM;
  short* const lb0 = &Bs[w * 1024];
  short* const lb1 = &Bs[w * 1024 + 512];

  const short* pa0 = nullptr; const short* pa1 = nullptr;
  short* la0 = nullptr; short* la1 = nullptr;
  const float* paf = nullptr; short* lafA = nullptr; short* lafB = nullptr;
  if constexpr (A_BF16) {
    pa0 = (const short*)Aptr + (size_t)(m0 + srow) * KDIM + scol;
    pa1 = pa0 + (size_t)16 * KDIM;
    la0 = &As[w * 1024];
    la1 = &As[w * 1024 + 512];
  } else {
    const int arow  = w * 32 + (lane >> 1);
    const int half  = lane & 1;
    const int phase = (lane >> 2) & 3;
    paf  = (const float*)Aptr + (size_t)(m0 + arow) * KDIM + half * 16;
    lafA = &As[arow * 32 + ((2 * half)     ^ phase) * 8];
    lafB = &As[arow * 32 + ((2 * half + 1) ^ phase) * 8];
  }

  const int sread = (kg ^ ((rl >> 1) & 3)) * 8;

  for (int k0 = 0; k0 < KDIM; k0 += 32) {
    __syncthreads();
    if constexpr (A_BF16) {
      gload16(pa0 + k0, la0);
      gload16(pa1 + k0, la1);
    } else {
      const float* p = paf + k0;
      f32x4 f0 = *reinterpret_cast<const f32x4*>(p);
      f32x4 f1 = *reinterpret_cast<const f32x4*>(p + 4);
      f32x4 f2 = *reinterpret_cast<const f32x4*>(p + 8);
      f32x4 f3 = *reinterpret_cast<const f32x4*>(p + 12);
      short8 lo, hi;
      #pragma unroll
      for (int j = 0; j < 4; ++j) {
        lo[j] = f2bs(f0[j]); lo[4 + j] = f2bs(f1[j]);
        hi[j] = f2bs(f2[j]); hi[4 + j] = f2bs(f3[j]);
      }
      *reinterpret_cast<short8*>(lafA) = lo;
      *reinterpret_cast<short8*>(lafB) = hi;
    }
    gload16(pb0 + k0, lb0);
    gload16(pb1 + k0, lb1);
    __syncthreads();

    short8 af[4], bf[4];
    #pragma unroll
    for (int i = 0; i < 4; ++i) {
      af[i] = *reinterpret_cast<short8*>(&As[(wr * 64 + i * 16 + rl) * 32 + sread]);
      bf[i] = *reinterpret_cast<short8*>(&Bs[(wc * 64 + i * 16 + rl) * 32 + sread]);
    }
    #pragma unroll
    for (int mi = 0; mi < 4; ++mi)
      #pragma unroll
      for (int ni = 0; ni < 4; ++ni)
        acc[mi][ni] = __builtin_amdgcn_mfma_f32_16x16x32_bf16(
            af[mi], bf[ni], acc[mi][ni], 0, 0, 0);
  }

  #pragma unroll
  for (int ni = 0; ni < 4; ++ni) {
    const int col = n0 + wc * 64 + ni * 16 + rl;
    const float bv = bias[col];
    #pragma unroll
    for (int mi = 0; mi < 4; ++mi) {
      #pragma unroll
      for (int r = 0; r < 4; ++r) {
        const int row = m0 + wr * 64 + mi * 16 + kg * 4 + r;
        const float v = acc[mi][ni][r] + bv;
        if constexpr (OUT_BF16)
          ((short*)outptr)[(size_t)row * N + col] = f2bs(v);
        else
          ((float*)outptr)[(size_t)row * N + col] = v;
      }
    }
  }
}

// ---------------------------------------------------------------------------
// MFMA flash attention v3 (causal): swapped QK^T (S^T = K·Q^T) with 32x32x16
// MFMA, fully in-register softmax (lane owns one q-row: q = lane&31), P^T
// assembled in-register via bf16 pair-pack + __shfl_xor(32) + cndmask selects;
// PV computes O^T = V^T · P^T. No P LDS, no ones-MFMA, exp2-domain softmax.
// Block = 4 waves x 32 q-rows; q-tiles {pair, 15-pair}; K via global_load_lds
// double-buffered (XOR-swizzled source), V reg-staged transposed.
// ---------------------------------------------------------------------------
__global__ __launch_bounds__(256) void attn_mfma3_kernel(
    const short* __restrict__ qkv, short* __restrict__ y)
{
  __shared__ short Ks[2][64 * 64];
  __shared__ short Vt[2][64 * 64];

  const int tid  = threadIdx.x;
  const int lane = tid & 63;
  const int w    = tid >> 6;
  const int q32  = lane & 31;
  const int hi   = lane >> 5;

  const int bid  = blockIdx.x;
  const int pair = bid >> 6;            // 0..7
  const int bh   = bid & 63;
  const int b    = bh >> 4, h = bh & 15;
  const size_t bT = (size_t)b * T_;

  // K staging: thread tid covers LDS shorts [tid*8, tid*8+8): row=tid>>3,
  // phys slot = tid&7 holds logical slot (tid&7)^(row&7).
  const int kr0 = tid >> 3;
  const int kl0 = (tid & 7) ^ ((tid >> 3) & 7);
  const int kr1 = (tid + 256) >> 3;
  const int kl1 = (tid & 7) ^ (((tid + 256) >> 3) & 7);
  const size_t kbase0 = (bT + kr0) * N_QKV + C_ + h * HD + kl0 * 8;
  const size_t kbase1 = (bT + kr1) * N_QKV + C_ + h * HD + kl1 * 8;
  short* const kdst0 = &Ks[0][(w * 64) * 8];
  short* const kdst1 = &Ks[0][(w * 64 + 256) * 8];

  // V staging: thread covers key=tid&63, d in [w*16, w*16+16)
  const int vkey = tid & 63;
  const int vd16 = (tid >> 6) * 16;
  const size_t vbase = (bT + vkey) * N_QKV + 2 * C_ + h * HD + vd16;

  const int ksl = q32 & 7;              // swizzle phase for frag reads

  #pragma unroll 1
  for (int sel = 0; sel < 2; ++sel) {
    const int qi  = sel ? (15 - pair) : pair;
    const int nkb = 2 * qi + 2;
    const int wq0 = qi * 128 + w * 32;
    const int q   = wq0 + q32;          // this lane's q-row

    // Q B-frags: col=q (lane&31), k = d = kd*16 + hi*8 + j
    short8 qf[4];
    #pragma unroll
    for (int kd = 0; kd < 4; ++kd)
      qf[kd] = *reinterpret_cast<const short8*>(
          qkv + (bT + q) * N_QKV + h * HD + kd * 16 + hi * 8);

    f32x16 o0 = {}, o1 = {};            // O^T, d-tiles 0/1 (d = dt*32 + ...)
    float m_ = -INFINITY, l_ = 0.f;

    // prologue: stage tile 0 into buffer 0
    {
      gload16(qkv + kbase0, kdst0);
      gload16(qkv + kbase1, kdst1);
      short8 va = *reinterpret_cast<const short8*>(qkv + vbase);
      short8 vb = *reinterpret_cast<const short8*>(qkv + vbase + 8);
      #pragma unroll
      for (int j = 0; j < 8; ++j) {
        Vt[0][(vd16 + j) * 64 + (((vkey >> 3) ^ j) << 3) + (vkey & 7)]     = va[j];
        Vt[0][(vd16 + 8 + j) * 64 + (((vkey >> 3) ^ j) << 3) + (vkey & 7)] = vb[j];
      }
    }
    __syncthreads();

    int cur = 0;
    for (int kb = 0; kb < nkb; ++kb) {
      const bool more = (kb + 1 < nkb);
      short8 va, vb;
      if (more) {
        const size_t koff = (size_t)(kb + 1) * 64 * N_QKV;
        gload16(qkv + kbase0 + koff, kdst0 + (cur ^ 1) * 4096);
        gload16(qkv + kbase1 + koff, kdst1 + (cur ^ 1) * 4096);
        va = *reinterpret_cast<const short8*>(qkv + vbase + koff);
        vb = *reinterpret_cast<const short8*>(qkv + vbase + koff + 8);
      }

      const int kmin = kb * 64;
      if (kmin <= wq0 + 31) {
        const short* ksc = &Ks[cur][0];
        const short* vtc = &Vt[cur][0];

        // ---- QK^T (swapped): s0/s1 = S^T tiles, keys c*32 + (e&3)+8*(e>>2)+4*hi
        f32x16 s0 = {}, s1 = {};
        #pragma unroll
        for (int kd = 0; kd < 4; ++kd) {
          const int sl = ((2 * kd + hi) ^ ksl) * 8;
          short8 kf0 = *reinterpret_cast<const short8*>(&ksc[q32 * 64 + sl]);
          short8 kf1 = *reinterpret_cast<const short8*>(&ksc[(32 + q32) * 64 + sl]);
          s0 = __builtin_amdgcn_mfma_f32_32x32x16_bf16(kf0, qf[kd], s0, 0, 0, 0);
          s1 = __builtin_amdgcn_mfma_f32_32x32x16_bf16(kf1, qf[kd], s1, 0, 0, 0);
        }

        // ---- scale (+ causal mask) in exp2 domain ----
        const bool needmask = (kmin + 63 > wq0);
        if (needmask) {
          const int qrel = q - kmin - 4 * hi;
          #pragma unroll
          for (int e = 0; e < 16; ++e) {
            const int ko = (e & 3) + 8 * (e >> 2);
            s0[e] = (ko > qrel)      ? -INFINITY : s0[e] * SCALE2;
            s1[e] = (ko + 32 > qrel) ? -INFINITY : s1[e] * SCALE2;
          }
        } else {
          #pragma unroll
          for (int e = 0; e < 16; ++e) { s0[e] *= SCALE2; s1[e] *= SCALE2; }
        }

        // ---- per-lane row stats: local reduce + one xor-32 shuffle ----
        float mx = s0[0];
        #pragma unroll
        for (int e = 1; e < 16; ++e) mx = fmaxf(mx, s0[e]);
        #pragma unroll
        for (int e = 0; e < 16; ++e) mx = fmaxf(mx, s1[e]);
        mx = fmaxf(mx, __shfl_xor(mx, 32, 64));
        const float mn = fmaxf(m_, mx);
        const float cr = exp2f(m_ - mn);
        m_ = mn;
        float rs = 0.f;
        #pragma unroll
        for (int e = 0; e < 16; ++e) {
          s0[e] = exp2f(s0[e] - mn); rs += s0[e];
          s1[e] = exp2f(s1[e] - mn); rs += s1[e];
        }
        rs += __shfl_xor(rs, 32, 64);
        l_ = l_ * cr + rs;
        #pragma unroll
        for (int e = 0; e < 16; ++e) { o0[e] *= cr; o1[e] *= cr; }

        // ---- P^T B-frags in-register: pack bf16 pairs, xor-32, select ----
        unsigned pk[2][4][2], sw[2][4][2];
        #pragma unroll
        for (int g = 0; g < 4; ++g)
          #pragma unroll
          for (int p = 0; p < 2; ++p) {
            pk[0][g][p] = pack2(s0[4 * g + 2 * p], s0[4 * g + 2 * p + 1]);
            pk[1][g][p] = pack2(s1[4 * g + 2 * p], s1[4 * g + 2 * p + 1]);
            sw[0][g][p] = (unsigned)__shfl_xor((int)pk[0][g][p], 32, 64);
            sw[1][g][p] = (unsigned)__shfl_xor((int)pk[1][g][p], 32, 64);
          }

        #pragma unroll
        for (int kk = 0; kk < 4; ++kk) {
          const int c = kk >> 1, a2 = 2 * (kk & 1);
          u32x4 t;
          t[0] = hi ? sw[c][a2 + 1][0] : pk[c][a2][0];
          t[1] = hi ? sw[c][a2 + 1][1] : pk[c][a2][1];
          t[2] = hi ? pk[c][a2 + 1][0] : sw[c][a2][0];
          t[3] = hi ? pk[c][a2 + 1][1] : sw[c][a2][1];
          const short8 pb = __builtin_bit_cast(short8, t);
          const int sl = ((2 * kk + hi) ^ ksl) * 8;
          short8 vf0 = *reinterpret_cast<const short8*>(&vtc[q32 * 64 + sl]);
          short8 vf1 = *reinterpret_cast<const short8*>(&vtc[(32 + q32) * 64 + sl]);
          o0 = __builtin_amdgcn_mfma_f32_32x32x16_bf16(vf0, pb, o0, 0, 0, 0);
          o1 = __builtin_amdgcn_mfma_f32_32x32x16_bf16(vf1, pb, o1, 0, 0, 0);
        }
      }

      if (more) {
        #pragma unroll
        for (int j = 0; j < 8; ++j) {
          Vt[cur ^ 1][(vd16 + j) * 64 + (((vkey >> 3) ^ j) << 3) + (vkey & 7)]     = va[j];
          Vt[cur ^ 1][(vd16 + 8 + j) * 64 + (((vkey >> 3) ^ j) << 3) + (vkey & 7)] = vb[j];
        }
      }
      __syncthreads();
      cur ^= 1;
    }

    // ---- epilogue: O^T row d = dt*32 + 8g + 4hi + t, col q; bs4 stores ----
    const float inv = 1.f / l_;
    short* const yp = y + (bT + q) * C_ + h * HD;
    #pragma unroll
    for (int g = 0; g < 4; ++g) {
      bs4 ov0, ov1;
      #pragma unroll
      for (int t = 0; t < 4; ++t) {
        ov0[t] = f2bs(o0[4 * g + t] * inv);
        ov1[t] = f2bs(o1[4 * g + t] * inv);
      }
      *reinterpret_cast<bs4*>(yp + 8 * g + 4 * hi)      = ov0;
      *reinterpret_cast<bs4*>(yp + 32 + 8 * g + 4 * hi) = ov1;
    }
  }
}

extern "C" void kernel_launch(void* const* d_in, const int* in_sizes, int n_in,
                              void* d_out, int out_size, void* d_ws, size_t ws_size,
                              hipStream_t stream) {
  const float* x  = (const float*)d_in[0];
  const float* Wa = (const float*)d_in[1];
  const float* ba = (const float*)d_in[2];
  const float* Wp = (const float*)d_in[3];
  const float* bp = (const float*)d_in[4];

  short* qkvb = (short*)d_ws;                       // [8192,3072] bf16 (50.3MB)
  short* yb   = qkvb + (size_t)M_ * N_QKV;          // [8192,1024] bf16 (16.8MB)
  short* WaT  = yb + (size_t)M_ * C_;               // [3072,1024] bf16 (6.3MB)
  short* WpT  = WaT;                                // overlaid

  wtrans_kernel<<<(KDIM / 32) * (N_QKV / 32), 256, 0, stream>>>(Wa, WaT, N_QKV);
  gemm128_kernel<false, true><<<(M_ / 128) * (N_QKV / 128), 256, 0, stream>>>(
      x, WaT, ba, qkvb, N_QKV);
  wtrans_kernel<<<(KDIM / 32) * (C_ / 32), 256, 0, stream>>>(Wp, WpT, C_);
  attn_mfma3_kernel<<<8 * B_ * NH, 256, 0, stream>>>(qkvb, yb);
  gemm128_kernel<true, false><<<(M_ / 128) * (C_ / 128), 256, 0, stream>>>(
      yb, WpT, bp, d_out, C_);
}

// Round 6
// 228.991 us; speedup vs baseline: 11.3056x; 1.0278x over previous
//
#include <hip/hip_runtime.h>
#include <hip/hip_bf16.h>
#include <math.h>

// Problem constants: B=4, T=2048, C=1024, H=16, D=64
#define B_  4
#define T_  2048
#define C_  1024
#define NH  16
#define HD  64
#define M_  (B_ * T_)        // 8192 rows
#define N_QKV (3 * C_)       // 3072
#define KDIM 1024
#define SCALE2 0.18033688011112042f   // (1/sqrt(64)) * log2(e), prefolded into Q

typedef __attribute__((ext_vector_type(8))) short short8;
typedef __attribute__((ext_vector_type(4))) short bs4;
typedef __attribute__((ext_vector_type(4))) float f32x4;
typedef __attribute__((ext_vector_type(16))) float f32x16;
typedef __attribute__((ext_vector_type(4))) unsigned u32x4;

__device__ __forceinline__ short f2bs(float f) {
  __hip_bfloat16 h = __float2bfloat16(f);
  return *reinterpret_cast<short*>(&h);
}
__device__ __forceinline__ unsigned pack2(float a, float b) {
  return (unsigned)(unsigned short)f2bs(a) | ((unsigned)(unsigned short)f2bs(b) << 16);
}

__device__ __forceinline__ void gload16(const void* g, void* l) {
  __builtin_amdgcn_global_load_lds(
      (const __attribute__((address_space(1))) void*)g,
      (__attribute__((address_space(3))) void*)l, 16, 0, 0);
}

// ---------------------------------------------------------------------------
// Transpose + convert: W [KDIM][Ncols] f32 -> Wt [Ncols][KDIM] bf16.
// Columns < qcols are pre-scaled by SCALE2 (folds attention scale into Q).
// ---------------------------------------------------------------------------
__global__ __launch_bounds__(256) void wtrans_kernel(
    const float* __restrict__ W, short* __restrict__ Wt, int Ncols, int qcols)
{
  __shared__ short t[32][33];
  const int nb = Ncols / 32;
  const int bn = blockIdx.x % nb, bk = blockIdx.x / nb;
  const int tid = threadIdx.x;
  const int r = tid >> 3, c4 = (tid & 7) * 4;
  const float cs = (bn * 32 < qcols) ? SCALE2 : 1.f;
  f32x4 v = *reinterpret_cast<const f32x4*>(
      W + (size_t)(bk * 32 + r) * Ncols + bn * 32 + c4);
  #pragma unroll
  for (int j = 0; j < 4; ++j) t[r][c4 + j] = f2bs(v[j] * cs);
  __syncthreads();
  bs4 o;
  #pragma unroll
  for (int j = 0; j < 4; ++j) o[j] = t[c4 + j][r];
  *reinterpret_cast<bs4*>(Wt + (size_t)(bn * 32 + r) * KDIM + bk * 32 + c4) = o;
}

// ---------------------------------------------------------------------------
// GEMM: out[M,N] = A[M,1024] @ Bt[N,1024]^T + bias[N]
// bias columns < nq are scaled by SCALE2 (to match pre-scaled W columns).
// ---------------------------------------------------------------------------
template<bool A_BF16, bool OUT_BF16>
__global__ __launch_bounds__(256) void gemm128_kernel(
    const void* __restrict__ Aptr, const short* __restrict__ Bt,
    const float* __restrict__ bias, void* __restrict__ outptr, int N, int nq)
{
  __shared__ short As[128 * 32];
  __shared__ short Bs[128 * 32];

  const int tid  = threadIdx.x;
  const int lane = tid & 63;
  const int w    = tid >> 6;
  const int wr   = w >> 1, wc = w & 1;
  const int rl   = lane & 15, kg = lane >> 4;
  const int nblk = N >> 7;
  const int m0 = (blockIdx.x / nblk) << 7;
  const int n0 = (blockIdx.x % nblk) << 7;

  f32x4 acc[4][4] = {};

  const int srow = w * 32 + (lane >> 2);
  const int scol = ((lane & 3) ^ ((lane >> 3) & 3)) * 8;
  const short* pb0 = Bt + (size_t)(n0 + srow) * KDIM + scol;
  const short* pb1 = pb0 + (size_t)16 * KDIM;
  short* const lb0 = &Bs[w * 1024];
  short* const lb1 = &Bs[w * 1024 + 512];

  const short* pa0 = nullptr; const short* pa1 = nullptr;
  short* la0 = nullptr; short* la1 = nullptr;
  const float* paf = nullptr; short* lafA = nullptr; short* lafB = nullptr;
  if constexpr (A_BF16) {
    pa0 = (const short*)Aptr + (size_t)(m0 + srow) * KDIM + scol;
    pa1 = pa0 + (size_t)16 * KDIM;
    la0 = &As[w * 1024];
    la1 = &As[w * 1024 + 512];
  } else {
    const int arow  = w * 32 + (lane >> 1);
    const int half  = lane & 1;
    const int phase = (lane >> 2) & 3;
    paf  = (const float*)Aptr + (size_t)(m0 + arow) * KDIM + half * 16;
    lafA = &As[arow * 32 + ((2 * half)     ^ phase) * 8];
    lafB = &As[arow * 32 + ((2 * half + 1) ^ phase) * 8];
  }

  const int sread = (kg ^ ((rl >> 1) & 3)) * 8;

  for (int k0 = 0; k0 < KDIM; k0 += 32) {
    __syncthreads();
    if constexpr (A_BF16) {
      gload16(pa0 + k0, la0);
      gload16(pa1 + k0, la1);
    } else {
      const float* p = paf + k0;
      f32x4 f0 = *reinterpret_cast<const f32x4*>(p);
      f32x4 f1 = *reinterpret_cast<const f32x4*>(p + 4);
      f32x4 f2 = *reinterpret_cast<const f32x4*>(p + 8);
      f32x4 f3 = *reinterpret_cast<const f32x4*>(p + 12);
      short8 lo, hi;
      #pragma unroll
      for (int j = 0; j < 4; ++j) {
        lo[j] = f2bs(f0[j]); lo[4 + j] = f2bs(f1[j]);
        hi[j] = f2bs(f2[j]); hi[4 + j] = f2bs(f3[j]);
      }
      *reinterpret_cast<short8*>(lafA) = lo;
      *reinterpret_cast<short8*>(lafB) = hi;
    }
    gload16(pb0 + k0, lb0);
    gload16(pb1 + k0, lb1);
    __syncthreads();

    short8 af[4], bf[4];
    #pragma unroll
    for (int i = 0; i < 4; ++i) {
      af[i] = *reinterpret_cast<short8*>(&As[(wr * 64 + i * 16 + rl) * 32 + sread]);
      bf[i] = *reinterpret_cast<short8*>(&Bs[(wc * 64 + i * 16 + rl) * 32 + sread]);
    }
    #pragma unroll
    for (int mi = 0; mi < 4; ++mi)
      #pragma unroll
      for (int ni = 0; ni < 4; ++ni)
        acc[mi][ni] = __builtin_amdgcn_mfma_f32_16x16x32_bf16(
            af[mi], bf[ni], acc[mi][ni], 0, 0, 0);
  }

  #pragma unroll
  for (int ni = 0; ni < 4; ++ni) {
    const int col = n0 + wc * 64 + ni * 16 + rl;
    float bv = bias[col];
    if (col < nq) bv *= SCALE2;
    #pragma unroll
    for (int mi = 0; mi < 4; ++mi) {
      #pragma unroll
      for (int r = 0; r < 4; ++r) {
        const int row = m0 + wr * 64 + mi * 16 + kg * 4 + r;
        const float v = acc[mi][ni][r] + bv;
        if constexpr (OUT_BF16)
          ((short*)outptr)[(size_t)row * N + col] = f2bs(v);
        else
          ((float*)outptr)[(size_t)row * N + col] = v;
      }
    }
  }
}

// ---------------------------------------------------------------------------
// MFMA flash attention v4 (causal): swapped QK^T (S^T = K·Q^T), 32x32x16
// MFMA, in-register softmax (lane owns q-row = lane&31), in-register P^T
// assembly. ONE q-tile (128 rows) per block -> grid 1024 = 4 blocks/CU.
// Q pre-scaled by SCALE2 in the QKV GEMM (exp2-domain scores for free).
// Defer-max (THR=8): skip O-rescale when tile max grew < 8.
// qi = 15 - bid>>6: heaviest q-tiles dispatch first; bid%8=bh%8 pins each
// (b,h)'s q-tiles to one XCD for K/V L2 reuse.
// ---------------------------------------------------------------------------
__global__ __launch_bounds__(256) void attn_mfma4_kernel(
    const short* __restrict__ qkv, short* __restrict__ y)
{
  __shared__ short Ks[2][64 * 64];
  __shared__ short Vt[2][64 * 64];

  const int tid  = threadIdx.x;
  const int lane = tid & 63;
  const int w    = tid >> 6;
  const int q32  = lane & 31;
  const int hi   = lane >> 5;

  const int bid  = blockIdx.x;
  const int qi   = 15 - (bid >> 6);     // heavy blocks first
  const int bh   = bid & 63;
  const int b    = bh >> 4, h = bh & 15;
  const size_t bT = (size_t)b * T_;

  // K staging: thread tid covers LDS shorts [tid*8, tid*8+8): row=tid>>3,
  // phys slot = tid&7 holds logical slot (tid&7)^(row&7).
  const int kr0 = tid >> 3;
  const int kl0 = (tid & 7) ^ ((tid >> 3) & 7);
  const int kr1 = (tid + 256) >> 3;
  const int kl1 = (tid & 7) ^ (((tid + 256) >> 3) & 7);
  const size_t kbase0 = (bT + kr0) * N_QKV + C_ + h * HD + kl0 * 8;
  const size_t kbase1 = (bT + kr1) * N_QKV + C_ + h * HD + kl1 * 8;
  short* const kdst0 = &Ks[0][(w * 64) * 8];
  short* const kdst1 = &Ks[0][(w * 64 + 256) * 8];

  // V staging: thread covers key=tid&63, d in [w*16, w*16+16)
  const int vkey = tid & 63;
  const int vd16 = (tid >> 6) * 16;
  const size_t vbase = (bT + vkey) * N_QKV + 2 * C_ + h * HD + vd16;

  const int ksl = q32 & 7;              // swizzle phase for frag reads

  const int nkb = 2 * qi + 2;
  const int wq0 = qi * 128 + w * 32;
  const int q   = wq0 + q32;            // this lane's q-row

  // Q B-frags: col=q (lane&31), k = d = kd*16 + hi*8 + j  (pre-scaled)
  short8 qf[4];
  #pragma unroll
  for (int kd = 0; kd < 4; ++kd)
    qf[kd] = *reinterpret_cast<const short8*>(
        qkv + (bT + q) * N_QKV + h * HD + kd * 16 + hi * 8);

  f32x16 o0 = {}, o1 = {};              // O^T, d-tiles 0/1
  float m_ = -INFINITY, l_ = 0.f;

  // prologue: stage tile 0 into buffer 0
  {
    gload16(qkv + kbase0, kdst0);
    gload16(qkv + kbase1, kdst1);
    short8 va = *reinterpret_cast<const short8*>(qkv + vbase);
    short8 vb = *reinterpret_cast<const short8*>(qkv + vbase + 8);
    #pragma unroll
    for (int j = 0; j < 8; ++j) {
      Vt[0][(vd16 + j) * 64 + (((vkey >> 3) ^ j) << 3) + (vkey & 7)]     = va[j];
      Vt[0][(vd16 + 8 + j) * 64 + (((vkey >> 3) ^ j) << 3) + (vkey & 7)] = vb[j];
    }
  }
  __syncthreads();

  int cur = 0;
  for (int kb = 0; kb < nkb; ++kb) {
    const bool more = (kb + 1 < nkb);
    short8 va, vb;
    if (more) {
      const size_t koff = (size_t)(kb + 1) * 64 * N_QKV;
      gload16(qkv + kbase0 + koff, kdst0 + (cur ^ 1) * 4096);
      gload16(qkv + kbase1 + koff, kdst1 + (cur ^ 1) * 4096);
      va = *reinterpret_cast<const short8*>(qkv + vbase + koff);
      vb = *reinterpret_cast<const short8*>(qkv + vbase + koff + 8);
    }

    const int kmin = kb * 64;
    if (kmin <= wq0 + 31) {
      const short* ksc = &Ks[cur][0];
      const short* vtc = &Vt[cur][0];

      // ---- QK^T (swapped): keys = kmin + c*32 + (e&3)+8*(e>>2)+4*hi ----
      f32x16 s0 = {}, s1 = {};
      #pragma unroll
      for (int kd = 0; kd < 4; ++kd) {
        const int sl = ((2 * kd + hi) ^ ksl) * 8;
        short8 kf0 = *reinterpret_cast<const short8*>(&ksc[q32 * 64 + sl]);
        short8 kf1 = *reinterpret_cast<const short8*>(&ksc[(32 + q32) * 64 + sl]);
        s0 = __builtin_amdgcn_mfma_f32_32x32x16_bf16(kf0, qf[kd], s0, 0, 0, 0);
        s1 = __builtin_amdgcn_mfma_f32_32x32x16_bf16(kf1, qf[kd], s1, 0, 0, 0);
      }

      // ---- causal mask (scores already in exp2 domain via Q pre-scale) ----
      if (kmin + 63 > wq0) {
        const int qrel = q - kmin - 4 * hi;
        #pragma unroll
        for (int e = 0; e < 16; ++e) {
          const int ko = (e & 3) + 8 * (e >> 2);
          if (ko > qrel)      s0[e] = -INFINITY;
          if (ko + 32 > qrel) s1[e] = -INFINITY;
        }
      }

      // ---- row max: local reduce + one xor-32 shuffle ----
      float mx = s0[0];
      #pragma unroll
      for (int e = 1; e < 16; ++e) mx = fmaxf(mx, s0[e]);
      #pragma unroll
      for (int e = 0; e < 16; ++e) mx = fmaxf(mx, s1[e]);
      mx = fmaxf(mx, __shfl_xor(mx, 32, 64));

      // ---- defer-max: rescale only when max grew by > 8 (exp2 domain) ----
      if (!__all(mx <= m_ + 8.f)) {
        const float mn = fmaxf(m_, mx);
        const float cr = exp2f(m_ - mn);
        m_ = mn;
        l_ *= cr;
        #pragma unroll
        for (int e = 0; e < 16; ++e) { o0[e] *= cr; o1[e] *= cr; }
      }

      float rs = 0.f;
      #pragma unroll
      for (int e = 0; e < 16; ++e) {
        s0[e] = exp2f(s0[e] - m_); rs += s0[e];
        s1[e] = exp2f(s1[e] - m_); rs += s1[e];
      }
      rs += __shfl_xor(rs, 32, 64);
      l_ += rs;

      // ---- P^T B-frags in-register: pack bf16 pairs, xor-32, select ----
      unsigned pk[2][4][2], sw[2][4][2];
      #pragma unroll
      for (int g = 0; g < 4; ++g)
        #pragma unroll
        for (int p = 0; p < 2; ++p) {
          pk[0][g][p] = pack2(s0[4 * g + 2 * p], s0[4 * g + 2 * p + 1]);
          pk[1][g][p] = pack2(s1[4 * g + 2 * p], s1[4 * g + 2 * p + 1]);
          sw[0][g][p] = (unsigned)__shfl_xor((int)pk[0][g][p], 32, 64);
          sw[1][g][p] = (unsigned)__shfl_xor((int)pk[1][g][p], 32, 64);
        }

      #pragma unroll
      for (int kk = 0; kk < 4; ++kk) {
        const int c = kk >> 1, a2 = 2 * (kk & 1);
        u32x4 t;
        t[0] = hi ? sw[c][a2 + 1][0] : pk[c][a2][0];
        t[1] = hi ? sw[c][a2 + 1][1] : pk[c][a2][1];
        t[2] = hi ? pk[c][a2 + 1][0] : sw[c][a2][0];
        t[3] = hi ? pk[c][a2 + 1][1] : sw[c][a2][1];
        const short8 pb = __builtin_bit_cast(short8, t);
        const int sl = ((2 * kk + hi) ^ ksl) * 8;
        short8 vf0 = *reinterpret_cast<const short8*>(&vtc[q32 * 64 + sl]);
        short8 vf1 = *reinterpret_cast<const short8*>(&vtc[(32 + q32) * 64 + sl]);
        o0 = __builtin_amdgcn_mfma_f32_32x32x16_bf16(vf0, pb, o0, 0, 0, 0);
        o1 = __builtin_amdgcn_mfma_f32_32x32x16_bf16(vf1, pb, o1, 0, 0, 0);
      }
    }

    if (more) {
      #pragma unroll
      for (int j = 0; j < 8; ++j) {
        Vt[cur ^ 1][(vd16 + j) * 64 + (((vkey >> 3) ^ j) << 3) + (vkey & 7)]     = va[j];
        Vt[cur ^ 1][(vd16 + 8 + j) * 64 + (((vkey >> 3) ^ j) << 3) + (vkey & 7)] = vb[j];
      }
    }
    __syncthreads();
    cur ^= 1;
  }

  // ---- epilogue: O^T row d = dt*32 + 8g + 4hi + t, col q; bs4 stores ----
  const float inv = 1.f / l_;
  short* const yp = y + (bT + q) * C_ + h * HD;
  #pragma unroll
  for (int g = 0; g < 4; ++g) {
    bs4 ov0, ov1;
    #pragma unroll
    for (int t = 0; t < 4; ++t) {
      ov0[t] = f2bs(o0[4 * g + t] * inv);
      ov1[t] = f2bs(o1[4 * g + t] * inv);
    }
    *reinterpret_cast<bs4*>(yp + 8 * g + 4 * hi)      = ov0;
    *reinterpret_cast<bs4*>(yp + 32 + 8 * g + 4 * hi) = ov1;
  }
}

extern "C" void kernel_launch(void* const* d_in, const int* in_sizes, int n_in,
                              void* d_out, int out_size, void* d_ws, size_t ws_size,
                              hipStream_t stream) {
  const float* x  = (const float*)d_in[0];
  const float* Wa = (const float*)d_in[1];
  const float* ba = (const float*)d_in[2];
  const float* Wp = (const float*)d_in[3];
  const float* bp = (const float*)d_in[4];

  short* qkvb = (short*)d_ws;                       // [8192,3072] bf16 (50.3MB)
  short* yb   = qkvb + (size_t)M_ * N_QKV;          // [8192,1024] bf16 (16.8MB)
  short* WaT  = yb + (size_t)M_ * C_;               // [3072,1024] bf16 (6.3MB)
  short* WpT  = WaT;                                // overlaid

  // W_attn^T (q-columns pre-scaled by SCALE2)
  wtrans_kernel<<<(KDIM / 32) * (N_QKV / 32), 256, 0, stream>>>(Wa, WaT, N_QKV, C_);
  gemm128_kernel<false, true><<<(M_ / 128) * (N_QKV / 128), 256, 0, stream>>>(
      x, WaT, ba, qkvb, N_QKV, C_);
  wtrans_kernel<<<(KDIM / 32) * (C_ / 32), 256, 0, stream>>>(Wp, WpT, C_, 0);
  attn_mfma4_kernel<<<16 * B_ * NH, 256, 0, stream>>>(qkvb, yb);
  gemm128_kernel<true, false><<<(M_ / 128) * (C_ / 128), 256, 0, stream>>>(
      yb, WpT, bp, d_out, C_, 0);
}